// Round 11
// baseline (367.348 us; speedup 1.0000x reference)
//
#include <hip/hip_runtime.h>
#include <hip/hip_bf16.h>

#define DD 1024
#define NB 4
#define TT 1024
#define NH 16
#define NS 4
#define LKV 1028   // NS + TT
#define NCH 4
#define CHS 257    // keys per chunk (4*257 = 1028)

typedef __hip_bfloat16 bf16;
typedef __attribute__((ext_vector_type(8))) short short8;
typedef __attribute__((ext_vector_type(4))) float f32x4;

#define GLD16(gp, lp) __builtin_amdgcn_global_load_lds( \
    (const __attribute__((address_space(1))) unsigned int*)(const void*)(gp), \
    (__attribute__((address_space(3))) unsigned int*)(void*)(lp), 16, 0, 0)

__device__ __forceinline__ float warp_sum(float v) {
#pragma unroll
    for (int o = 32; o > 0; o >>= 1) v += __shfl_xor(v, o);
    return v;
}

__device__ __forceinline__ float b2f(unsigned short u) {
    union { unsigned int i; float f; } x; x.i = ((unsigned)u) << 16; return x.f;
}
__device__ __forceinline__ unsigned short f2b(float f) {
    bf16 h = __float2bfloat16(f);
    union { bf16 h; unsigned short u; } x; x.h = h; return x.u;
}

// ================= prep: cvt x + 6 weights, PE table, state copy ==============
struct PrepArgs {
    const float* cin[7];   // x, seW, oeW, sWk, sWv, oWk, oWv
    bf16* cout[7];
    const float* state0;
    float* cat;
    float* pe;
};

__global__ __launch_bounds__(256) void prep_kernel(PrepArgs a) {
    int bid = blockIdx.x;
    int tid = threadIdx.x;
    if (bid < 10240) {
        const float* in; bf16* out; size_t off;
        if (bid < 4096) { in = a.cin[0]; out = a.cout[0]; off = (size_t)bid * 1024; }
        else {
            int w = (bid - 4096) >> 10;
            in = a.cin[1 + w]; out = a.cout[1 + w];
            off = (size_t)((bid - 4096) & 1023) * 1024;
        }
        size_t i = off + tid * 4;
        float4 v = *(const float4*)(in + i);
        out[i + 0] = __float2bfloat16(v.x);
        out[i + 1] = __float2bfloat16(v.y);
        out[i + 2] = __float2bfloat16(v.z);
        out[i + 3] = __float2bfloat16(v.w);
    } else if (bid < 11264) {
        int t = bid - 10240;
#pragma unroll
        for (int i = 0; i < 2; ++i) {
            int j = i * 256 + tid;                       // 0..511
            float ang = (float)t * exp2f(-(float)j * (1.0f / 256.0f));
            a.pe[(size_t)t * DD + j]       = sinf(ang);
            a.pe[(size_t)t * DD + 512 + j] = cosf(ang);
        }
    } else {
        int r = bid - 11264;       // 0..15
        int b = r >> 2, s = r & 3;
#pragma unroll
        for (int i = 0; i < 4; ++i)
            a.cat[(size_t)(b * LKV + s) * DD + i * 256 + tid] =
                a.state0[(size_t)r * DD + i * 256 + tid];
    }
}

// ================= fused LayerNorm -> bf16 (state-kv rows + out token rows) ===
__global__ __launch_bounds__(256) void ln_fused_kernel(
    const float* __restrict__ cat, const float* __restrict__ cat2,
    bf16* __restrict__ lnbb, bf16* __restrict__ lnbb2,
    const float* __restrict__ sg, const float* __restrict__ sb,
    const float* __restrict__ og, const float* __restrict__ ob)
{
    int bid = blockIdx.x;
    int tid = threadIdx.x;
    const float* in; bf16* out; const float* g; const float* b;
    if (bid < 4112) {
        in = cat + (size_t)bid * DD; out = lnbb + (size_t)bid * DD; g = sg; b = sb;
    } else {
        int r = bid - 4112;
        int row = (r >> 10) * LKV + (r & 1023);
        in = cat2 + (size_t)row * DD; out = lnbb2 + (size_t)r * DD; g = og; b = ob;
    }
    float v[4];
    float s1 = 0.f, s2 = 0.f;
#pragma unroll
    for (int i = 0; i < 4; ++i) {
        v[i] = in[i * 256 + tid];
        s1 += v[i]; s2 += v[i] * v[i];
    }
    s1 = warp_sum(s1); s2 = warp_sum(s2);
    __shared__ float a1[4], a2[4];
    int w = tid >> 6;
    if ((tid & 63) == 0) { a1[w] = s1; a2[w] = s2; }
    __syncthreads();
    s1 = a1[0] + a1[1] + a1[2] + a1[3];
    s2 = a2[0] + a2[1] + a2[2] + a2[3];
    float mu  = s1 * (1.0f / DD);
    float var = s2 * (1.0f / DD) - mu * mu;
    var = var < 0.f ? 0.f : var;
    float rs = rsqrtf(var + 1e-5f);
#pragma unroll
    for (int i = 0; i < 4; ++i) {
        int c = i * 256 + tid;
        out[c] = __float2bfloat16((v[i] - mu) * rs * g[c] + b[c]);
    }
}

// ========== paired embed GEMM: one block computes se AND oe tiles =============
// grid 256 linear, XCD-swizzled. A(xb) staged once, both W tiles staged.
__global__ __launch_bounds__(256) void embed_pair_kernel(
    const bf16* __restrict__ xb,
    const bf16* __restrict__ seW, const bf16* __restrict__ oeW,
    const float* __restrict__ seb, const float* __restrict__ oeb,
    float* __restrict__ cat, float* __restrict__ cat2,
    const float* __restrict__ pe)
{
    __shared__ bf16 As[128 * 32];
    __shared__ bf16 W0s[128 * 32];
    __shared__ bf16 W1s[128 * 32];
    int bid = blockIdx.x;
    int t = (bid & 7) * 32 + (bid >> 3);   // bijective (256 = 8*32)
    int x = t & 7;
    int y = t >> 3;                        // 0..31
    int m0 = y * 128, n0 = x * 128;

    int tid = threadIdx.x, lane = tid & 63, wave = tid >> 6;
    int wm = (wave >> 1) << 6, wn = (wave & 1) << 6;
    f32x4 acc0[4][4] = {}, acc1[4][4] = {};
    int soff = wave * 1024 + lane * 16;
    int srow = soff >> 6, scol = (soff & 63) >> 1;
    char* lA0 = (char*)As  + wave * 1024; char* lA1 = (char*)As  + 4096 + wave * 1024;
    char* l00 = (char*)W0s + wave * 1024; char* l01 = (char*)W0s + 4096 + wave * 1024;
    char* l10 = (char*)W1s + wave * 1024; char* l11 = (char*)W1s + 4096 + wave * 1024;
    int fRow = lane & 15, kOff = (lane >> 4) << 3;

    for (int k0 = 0; k0 < DD; k0 += 32) {
        GLD16(xb  + (size_t)(m0 + srow) * DD + k0 + scol,      lA0);
        GLD16(xb  + (size_t)(m0 + 64 + srow) * DD + k0 + scol, lA1);
        GLD16(seW + (size_t)(n0 + srow) * DD + k0 + scol,      l00);
        GLD16(seW + (size_t)(n0 + 64 + srow) * DD + k0 + scol, l01);
        GLD16(oeW + (size_t)(n0 + srow) * DD + k0 + scol,      l10);
        GLD16(oeW + (size_t)(n0 + 64 + srow) * DD + k0 + scol, l11);
        __syncthreads();
        short8 a[4], b[4], c[4];
#pragma unroll
        for (int mi = 0; mi < 4; ++mi)
            a[mi] = *(const short8*)(As + (wm + mi * 16 + fRow) * 32 + kOff);
#pragma unroll
        for (int ni = 0; ni < 4; ++ni) {
            b[ni] = *(const short8*)(W0s + (wn + ni * 16 + fRow) * 32 + kOff);
            c[ni] = *(const short8*)(W1s + (wn + ni * 16 + fRow) * 32 + kOff);
        }
#pragma unroll
        for (int mi = 0; mi < 4; ++mi)
#pragma unroll
            for (int ni = 0; ni < 4; ++ni) {
                acc0[mi][ni] = __builtin_amdgcn_mfma_f32_16x16x32_bf16(
                    a[mi], b[ni], acc0[mi][ni], 0, 0, 0);
                acc1[mi][ni] = __builtin_amdgcn_mfma_f32_16x16x32_bf16(
                    a[mi], c[ni], acc1[mi][ni], 0, 0, 0);
            }
        __syncthreads();
    }

    int cCol = lane & 15, cRow4 = (lane >> 4) << 2;
#pragma unroll
    for (int mi = 0; mi < 4; ++mi)
#pragma unroll
        for (int ni = 0; ni < 4; ++ni)
#pragma unroll
            for (int r = 0; r < 4; ++r) {
                int row = m0 + wm + mi * 16 + cRow4 + r;
                int col = n0 + wn + ni * 16 + cCol;
                float p = pe[(size_t)(row & 1023) * DD + col];
                int bb = row >> 10, rr = row & 1023;
                cat [(size_t)(bb * LKV + NS + rr) * DD + col] = acc0[mi][ni][r] + seb[col] + p;
                cat2[(size_t)(bb * LKV + rr)      * DD + col] = acc1[mi][ni][r] + oeb[col] + p;
            }
}

// ========== paired K/V GEMM: one block computes K AND V tiles (shared A) ======
// grid 520 linear, XCD-swizzled: u<33 -> state branch (M=4112), else out tokens.
__global__ __launch_bounds__(256) void kv_pair_kernel(
    const bf16* __restrict__ lnbb, const bf16* __restrict__ lnbb2,
    const bf16* __restrict__ sWk, const bf16* __restrict__ sWv,
    const bf16* __restrict__ oWk, const bf16* __restrict__ oWv,
    const float* __restrict__ sbk, const float* __restrict__ sbv,
    const float* __restrict__ obk, const float* __restrict__ obv,
    bf16* __restrict__ kh, bf16* __restrict__ vh,
    bf16* __restrict__ kh2, bf16* __restrict__ vh2)
{
    __shared__ bf16 As[128 * 32];
    __shared__ bf16 Ks[128 * 32];
    __shared__ bf16 Vs[128 * 32];
    int bid = blockIdx.x;
    int t = (bid & 7) * 65 + (bid >> 3);   // bijective (520 = 8*65)
    int x = t & 7;
    int u = t >> 3;                        // 0..64
    int zp = (u < 33) ? 0 : 1;
    int y  = zp ? (u - 33) : u;
    const bf16* A  = zp ? lnbb2 : lnbb;
    const bf16* Wk = zp ? oWk : sWk;
    const bf16* Wv = zp ? oWv : sWv;
    const float* bk = zp ? obk : sbk;
    const float* bv = zp ? obv : sbv;
    bf16* ok = zp ? kh2 : kh;
    bf16* ov = zp ? vh2 : vh;
    int M = zp ? 4096 : 4112;
    int m0 = y * 128, n0 = x * 128;

    int tid = threadIdx.x, lane = tid & 63, wave = tid >> 6;
    int wm = (wave >> 1) << 6, wn = (wave & 1) << 6;
    f32x4 accK[4][4] = {}, accV[4][4] = {};
    int soff = wave * 1024 + lane * 16;
    int srow = soff >> 6, scol = (soff & 63) >> 1;
    char* lA0 = (char*)As + wave * 1024; char* lA1 = (char*)As + 4096 + wave * 1024;
    char* lK0 = (char*)Ks + wave * 1024; char* lK1 = (char*)Ks + 4096 + wave * 1024;
    char* lV0 = (char*)Vs + wave * 1024; char* lV1 = (char*)Vs + 4096 + wave * 1024;
    int fRow = lane & 15, kOff = (lane >> 4) << 3;

    for (int k0 = 0; k0 < DD; k0 += 32) {
        GLD16(A  + (size_t)(m0 + srow) * DD + k0 + scol,      lA0);
        GLD16(A  + (size_t)(m0 + 64 + srow) * DD + k0 + scol, lA1);
        GLD16(Wk + (size_t)(n0 + srow) * DD + k0 + scol,      lK0);
        GLD16(Wk + (size_t)(n0 + 64 + srow) * DD + k0 + scol, lK1);
        GLD16(Wv + (size_t)(n0 + srow) * DD + k0 + scol,      lV0);
        GLD16(Wv + (size_t)(n0 + 64 + srow) * DD + k0 + scol, lV1);
        __syncthreads();
        short8 a[4], b[4], c[4];
#pragma unroll
        for (int mi = 0; mi < 4; ++mi)
            a[mi] = *(const short8*)(As + (wm + mi * 16 + fRow) * 32 + kOff);
#pragma unroll
        for (int ni = 0; ni < 4; ++ni) {
            b[ni] = *(const short8*)(Ks + (wn + ni * 16 + fRow) * 32 + kOff);
            c[ni] = *(const short8*)(Vs + (wn + ni * 16 + fRow) * 32 + kOff);
        }
#pragma unroll
        for (int mi = 0; mi < 4; ++mi)
#pragma unroll
            for (int ni = 0; ni < 4; ++ni) {
                accK[mi][ni] = __builtin_amdgcn_mfma_f32_16x16x32_bf16(
                    a[mi], b[ni], accK[mi][ni], 0, 0, 0);
                accV[mi][ni] = __builtin_amdgcn_mfma_f32_16x16x32_bf16(
                    a[mi], c[ni], accV[mi][ni], 0, 0, 0);
            }
        __syncthreads();
    }

    int cCol = lane & 15, cRow4 = (lane >> 4) << 2;
#pragma unroll
    for (int mi = 0; mi < 4; ++mi)
#pragma unroll
        for (int ni = 0; ni < 4; ++ni)
#pragma unroll
            for (int r = 0; r < 4; ++r) {
                int row = m0 + wm + mi * 16 + cRow4 + r;
                int col = n0 + wn + ni * 16 + cCol;
                if (row < M) {
                    int orow = zp ? ((row >> 10) * LKV + (row & 1023)) : row;
                    ok[(size_t)orow * DD + col] = __float2bfloat16(accK[mi][ni][r] + bk[col]);
                    ov[(size_t)orow * DD + col] = __float2bfloat16(accV[mi][ni][r] + bv[col]);
                }
            }
}

// ================= copy lo[:, -1] =============================================
__global__ __launch_bounds__(256) void copy_lolast_kernel(
    const float* __restrict__ cat2, float* __restrict__ dst)
{
    int b = blockIdx.x;
    int tid = threadIdx.x;
#pragma unroll
    for (int i = 0; i < 4; ++i)
        dst[(size_t)b * DD + i * 256 + tid] =
            cat2[(size_t)(b * LKV + (TT - 1)) * DD + i * 256 + tid];
}

// ================= small-op device stages (mega-validated) ====================
template<int M>
__device__ void stage_rows_ln_bf16(
    const float* A, int row0, int rstride,
    const float* lng, const float* lnb,
    bf16* Asb, float* part1, float* part2)
{
    int tid = threadIdx.x, lane = tid & 63, w = tid >> 6;
#pragma unroll
    for (int i = 0; i < M; ++i) {
        const float* row = A + (size_t)(row0 + i * rstride) * DD;
        float4 v = *(const float4*)(row + tid * 4);
        float s1 = v.x + v.y + v.z + v.w;
        float s2 = v.x*v.x + v.y*v.y + v.z*v.z + v.w*v.w;
        s1 = warp_sum(s1); s2 = warp_sum(s2);
        if (lane == 0) { part1[i * 4 + w] = s1; part2[i * 4 + w] = s2; }
    }
    __syncthreads();
    float4 gv = *(const float4*)(lng + tid * 4);
    float4 bv = *(const float4*)(lnb + tid * 4);
#pragma unroll
    for (int i = 0; i < M; ++i) {
        float s1 = part1[i*4+0] + part1[i*4+1] + part1[i*4+2] + part1[i*4+3];
        float s2 = part2[i*4+0] + part2[i*4+1] + part2[i*4+2] + part2[i*4+3];
        float mu = s1 * (1.0f / DD);
        float var = s2 * (1.0f / DD) - mu * mu;
        var = var < 0.f ? 0.f : var;
        float rs = rsqrtf(var + 1e-5f);
        const float* row = A + (size_t)(row0 + i * rstride) * DD;
        float4 v = *(const float4*)(row + tid * 4);
        ushort4 o;
        o.x = f2b((v.x - mu) * rs * gv.x + bv.x);
        o.y = f2b((v.y - mu) * rs * gv.y + bv.y);
        o.z = f2b((v.z - mu) * rs * gv.z + bv.z);
        o.w = f2b((v.w - mu) * rs * gv.w + bv.w);
        *(ushort4*)(Asb + i * DD + tid * 4) = o;
    }
    __syncthreads();
}

template<int M>
__device__ void stage_rows_plain_bf16(const float* A, bf16* Asb)
{
    int tid = threadIdx.x;
#pragma unroll
    for (int i = 0; i < M; ++i) {
        float4 v = *(const float4*)(A + (size_t)i * DD + tid * 4);
        ushort4 o;
        o.x = f2b(v.x); o.y = f2b(v.y); o.z = f2b(v.z); o.w = f2b(v.w);
        *(ushort4*)(Asb + i * DD + tid * 4) = o;
    }
    __syncthreads();
}

template<int LQ>
__device__ void stage_combine(const float* pm, const float* pl,
                              const float* pacc, bf16* Asb)
{
    int tid = threadIdx.x;
    for (int idx = tid; idx < LQ * 4 * 256; idx += 256) {
        int m  = idx >> 8;
        int n4 = (idx & 255) * 4;
        int b = m / LQ, qi = m - b * LQ;
        int h = n4 >> 6, d = n4 & 63;
        int base = ((b * 16 + h) * 4 + qi) * NCH;
        float m0 = pm[base], m1 = pm[base+1], m2 = pm[base+2], m3 = pm[base+3];
        float Mx = fmaxf(fmaxf(m0, m1), fmaxf(m2, m3));
        float w0 = expf(m0-Mx), w1 = expf(m1-Mx), w2 = expf(m2-Mx), w3 = expf(m3-Mx);
        float L = pl[base]*w0 + pl[base+1]*w1 + pl[base+2]*w2 + pl[base+3]*w3;
        float inv = 1.f / L;
        float4 a0 = *(const float4*)(pacc + (size_t)(base+0)*64 + d);
        float4 a1 = *(const float4*)(pacc + (size_t)(base+1)*64 + d);
        float4 a2 = *(const float4*)(pacc + (size_t)(base+2)*64 + d);
        float4 a3 = *(const float4*)(pacc + (size_t)(base+3)*64 + d);
        ushort4 o;
        o.x = f2b((a0.x*w0 + a1.x*w1 + a2.x*w2 + a3.x*w3) * inv);
        o.y = f2b((a0.y*w0 + a1.y*w1 + a2.y*w2 + a3.y*w3) * inv);
        o.z = f2b((a0.z*w0 + a1.z*w1 + a2.z*w2 + a3.z*w3) * inv);
        o.w = f2b((a0.w*w0 + a1.w*w1 + a2.w*w2 + a3.w*w3) * inv);
        *(ushort4*)(Asb + m * DD + n4) = o;
    }
    __syncthreads();
}

template<int M>
__device__ void gemm_stage(const bf16* Asb, const float* W, const float* bias,
                           float* outf, const float* res, int gelu, int n)
{
    int lane = threadIdx.x & 63;
    const float* Wr = W + (size_t)n * DD;
    float acc[M] = {};
#pragma unroll
    for (int j = 0; j < 4; ++j) {
        float4 wv = *(const float4*)(Wr + j * 256 + lane * 4);
#pragma unroll
        for (int m = 0; m < M; ++m) {
            ushort4 av = *(const ushort4*)(Asb + m * DD + j * 256 + lane * 4);
            acc[m] += b2f(av.x)*wv.x + b2f(av.y)*wv.y
                    + b2f(av.z)*wv.z + b2f(av.w)*wv.w;
        }
    }
#pragma unroll
    for (int m = 0; m < M; ++m) acc[m] = warp_sum(acc[m]);
    if (lane == 0) {
#pragma unroll
        for (int m = 0; m < M; ++m) {
            float v = acc[m] + bias[n];
            if (gelu) v = 0.5f * v * (1.0f + erff(v * 0.70710678118654752f));
            if (res)  v += res[(size_t)m * DD + n];
            outf[(size_t)m * DD + n] = v;
        }
    }
}

// ================= small-op kernel wrappers ===================================
template<int M>
__global__ __launch_bounds__(256) void lngemm_kernel(
    const float* __restrict__ A, int row0, int rstride,
    const float* __restrict__ lng, const float* __restrict__ lnb,
    const float* __restrict__ W, const float* __restrict__ bias,
    float* __restrict__ outf, int gelu)
{
    __shared__ bf16 Asb[M * DD];
    __shared__ float part1[64], part2[64];
    stage_rows_ln_bf16<M>(A, row0, rstride, lng, lnb, Asb, part1, part2);
    gemm_stage<M>(Asb, W, bias, outf, nullptr, gelu, blockIdx.x * 4 + (threadIdx.x >> 6));
}

template<int M>
__global__ __launch_bounds__(256) void plaingemm_kernel(
    const float* __restrict__ A,
    const float* __restrict__ W, const float* __restrict__ bias,
    const float* __restrict__ res, float* __restrict__ outf, int gelu)
{
    __shared__ bf16 Asb[M * DD];
    stage_rows_plain_bf16<M>(A, Asb);
    gemm_stage<M>(Asb, W, bias, outf, res, gelu, blockIdx.x * 4 + (threadIdx.x >> 6));
}

template<int LQ>
__global__ __launch_bounds__(256) void comb_gemm_kernel(
    const float* __restrict__ pm, const float* __restrict__ pl,
    const float* __restrict__ pacc,
    const float* __restrict__ W, const float* __restrict__ bias,
    const float* __restrict__ res, float* __restrict__ outf)
{
    __shared__ bf16 Asb[LQ * 4 * DD];
    stage_combine<LQ>(pm, pl, pacc, Asb);
    gemm_stage<LQ * 4>(Asb, W, bias, outf, res, 0, blockIdx.x * 4 + (threadIdx.x >> 6));
}

// LN(stateNew) -> paired K,V state-row projections into kh2/vh2 (remapped rows)
__global__ __launch_bounds__(256) void kvpair_rows_kernel(
    const float* __restrict__ stateNew,
    const float* __restrict__ lng, const float* __restrict__ lnb,
    const float* __restrict__ Wk, const float* __restrict__ bk,
    const float* __restrict__ Wv, const float* __restrict__ bv,
    bf16* __restrict__ kh2, bf16* __restrict__ vh2)
{
    __shared__ bf16 Asb[16 * DD];
    __shared__ float part1[64], part2[64];
    stage_rows_ln_bf16<16>(stateNew, 0, 1, lng, lnb, Asb, part1, part2);
    int lane = threadIdx.x & 63;
    int n = blockIdx.x * 4 + (threadIdx.x >> 6);
    const float* WrK = Wk + (size_t)n * DD;
    const float* WrV = Wv + (size_t)n * DD;
    float accK[16] = {}, accV[16] = {};
#pragma unroll
    for (int j = 0; j < 4; ++j) {
        float4 wk4 = *(const float4*)(WrK + j * 256 + lane * 4);
        float4 wv4 = *(const float4*)(WrV + j * 256 + lane * 4);
#pragma unroll
        for (int m = 0; m < 16; ++m) {
            ushort4 av = *(const ushort4*)(Asb + m * DD + j * 256 + lane * 4);
            float ax = b2f(av.x), ay = b2f(av.y), az = b2f(av.z), aw = b2f(av.w);
            accK[m] += ax*wk4.x + ay*wk4.y + az*wk4.z + aw*wk4.w;
            accV[m] += ax*wv4.x + ay*wv4.y + az*wv4.z + aw*wv4.w;
        }
    }
#pragma unroll
    for (int m = 0; m < 16; ++m) { accK[m] = warp_sum(accK[m]); accV[m] = warp_sum(accV[m]); }
    if (lane == 0) {
#pragma unroll
        for (int m = 0; m < 16; ++m) {
            int orow = (m >> 2) * LKV + TT + (m & 3);
            kh2[(size_t)orow * DD + n] = __float2bfloat16(accK[m] + bk[n]);
            vh2[(size_t)orow * DD + n] = __float2bfloat16(accV[m] + bv[n]);
        }
    }
}

// ================= split-K flash-decode attention =============================
template<int LQ>
__global__ __launch_bounds__(256) void attn_part_kernel(
    const float* __restrict__ qh, const bf16* __restrict__ kh,
    const bf16* __restrict__ vh, float* __restrict__ pm,
    float* __restrict__ pl, float* __restrict__ pacc)
{
    int blk = blockIdx.x;
    int c  = blk & (NCH - 1);
    int bh = blk >> 2;
    int b = bh >> 4, h = bh & 15;
    int tid = threadIdx.x;
    int lane = tid & 63, w = tid >> 6;

    __shared__ float qs[LQ][64];
    __shared__ float sc[LQ][CHS];
    __shared__ float redm[4][LQ];
    __shared__ float redl[4][LQ];
    __shared__ float paccs[4][LQ][64];

    if (w < LQ) qs[w][lane] = qh[(size_t)(b * LQ + w) * DD + h * 64 + lane];
    __syncthreads();

    int kbeg = c * CHS;
    for (int t = tid; t < CHS; t += 256) {
        const ushort4* kr = (const ushort4*)((const unsigned short*)kh
            + (size_t)(b * LKV + kbeg + t) * DD + h * 64);
        float kf[64];
#pragma unroll
        for (int i = 0; i < 16; ++i) {
            ushort4 kk = kr[i];
            kf[i*4+0] = b2f(kk.x); kf[i*4+1] = b2f(kk.y);
            kf[i*4+2] = b2f(kk.z); kf[i*4+3] = b2f(kk.w);
        }
#pragma unroll
        for (int qi = 0; qi < LQ; ++qi) {
            float s = 0.f;
#pragma unroll
            for (int d = 0; d < 64; ++d) s += qs[qi][d] * kf[d];
            sc[qi][t] = s * 0.125f;
        }
    }
    __syncthreads();

    float M[LQ], L[LQ];
#pragma unroll
    for (int qi = 0; qi < LQ; ++qi) {
        float lm = -1e30f;
        for (int t = tid; t < CHS; t += 256) lm = fmaxf(lm, sc[qi][t]);
#pragma unroll
        for (int o = 32; o > 0; o >>= 1) lm = fmaxf(lm, __shfl_xor(lm, o));
        if (lane == 0) redm[w][qi] = lm;
    }
    __syncthreads();
#pragma unroll
    for (int qi = 0; qi < LQ; ++qi)
        M[qi] = fmaxf(fmaxf(redm[0][qi], redm[1][qi]), fmaxf(redm[2][qi], redm[3][qi]));

#pragma unroll
    for (int qi = 0; qi < LQ; ++qi) {
        float ls = 0.f;
        for (int t = tid; t < CHS; t += 256) {
            float e = expf(sc[qi][t] - M[qi]);
            sc[qi][t] = e;
            ls += e;
        }
        ls = warp_sum(ls);
        if (lane == 0) redl[w][qi] = ls;
    }
    __syncthreads();
#pragma unroll
    for (int qi = 0; qi < LQ; ++qi)
        L[qi] = redl[0][qi] + redl[1][qi] + redl[2][qi] + redl[3][qi];

    {
        int k0 = w * 65;
        int k1 = (k0 + 65 < CHS) ? k0 + 65 : CHS;
        float acc[LQ] = {};
        const unsigned short* vb = (const unsigned short*)vh
            + (size_t)(b * LKV + kbeg) * DD + h * 64 + lane;
        for (int k = k0; k < k1; ++k) {
            float v = b2f(vb[(size_t)k * DD]);
#pragma unroll
            for (int qi = 0; qi < LQ; ++qi) acc[qi] += sc[qi][k] * v;
        }
#pragma unroll
        for (int qi = 0; qi < LQ; ++qi) paccs[w][qi][lane] = acc[qi];
    }
    __syncthreads();
    if (tid < 64) {
#pragma unroll
        for (int qi = 0; qi < LQ; ++qi) {
            float s = paccs[0][qi][tid] + paccs[1][qi][tid]
                    + paccs[2][qi][tid] + paccs[3][qi][tid];
            pacc[(size_t)((bh * 4 + qi) * NCH + c) * 64 + tid] = s;
        }
    }
    if (tid < LQ) {
        pm[(bh * 4 + tid) * NCH + c] = M[tid];
        pl[(bh * 4 + tid) * NCH + c] = L[tid];
    }
}

// ========== fused gate: LN(lat2) -> logits -> top2 -> state update ============
__global__ __launch_bounds__(256) void gate_fused_kernel(
    const float* __restrict__ lat2,
    const float* __restrict__ lng, const float* __restrict__ lnb,
    const float* __restrict__ ctx,
    const float* __restrict__ state_old, float* __restrict__ stateNew,
    float* __restrict__ dout)
{
    int b = blockIdx.x;
    int tid = threadIdx.x;
    int lane = tid & 63, w = tid >> 6;
    __shared__ float logit[NS];
    __shared__ float alpha[NS];

    {
        const float* row = lat2 + (size_t)(b * NS + w) * DD;
        float4 v[4];
        float s1 = 0.f, s2 = 0.f;
#pragma unroll
        for (int j = 0; j < 4; ++j) {
            v[j] = *(const float4*)(row + (j * 64 + lane) * 4);
            s1 += v[j].x + v[j].y + v[j].z + v[j].w;
            s2 += v[j].x*v[j].x + v[j].y*v[j].y + v[j].z*v[j].z + v[j].w*v[j].w;
        }
        s1 = warp_sum(s1); s2 = warp_sum(s2);
        float mu = s1 * (1.0f / DD);
        float var = s2 * (1.0f / DD) - mu * mu;
        var = var < 0.f ? 0.f : var;
        float rs = rsqrtf(var + 1e-5f);
        float dot = 0.f;
#pragma unroll
        for (int j = 0; j < 4; ++j) {
            int c = (j * 64 + lane) * 4;
            float4 gv = *(const float4*)(lng + c);
            float4 bv = *(const float4*)(lnb + c);
            float4 cv = *(const float4*)(ctx + c);
            dot += ((v[j].x - mu) * rs * gv.x + bv.x) * cv.x
                 + ((v[j].y - mu) * rs * gv.y + bv.y) * cv.y
                 + ((v[j].z - mu) * rs * gv.z + bv.z) * cv.z
                 + ((v[j].w - mu) * rs * gv.w + bv.w) * cv.w;
        }
        dot = warp_sum(dot);
        if (lane == 0) logit[w] = dot;
    }
    __syncthreads();
    if (tid == 0) {
        float l[NS];
        for (int s = 0; s < NS; ++s) l[s] = logit[s];
        int i0 = 0;
        for (int s = 1; s < NS; ++s) if (l[s] > l[i0]) i0 = s;
        int i1 = (i0 == 0) ? 1 : 0;
        for (int s = 0; s < NS; ++s) if (s != i0 && l[s] > l[i1]) i1 = s;
        float mx = fmaxf(l[i0], l[i1]);
        float e0 = expf(l[i0] - mx), e1 = expf(l[i1] - mx);
        float inv = 1.f / (e0 + e1);
        for (int s = 0; s < NS; ++s) alpha[s] = 0.f;
        alpha[i0] = e0 * inv;
        alpha[i1] += e1 * inv;
        dout[4096 + b * 2 + 0] = (float)i0;
        dout[4096 + b * 2 + 1] = (float)i1;
    }
    __syncthreads();
    for (int idx = tid; idx < NS * DD; idx += 256) {
        int s = idx >> 10;
        float so = state_old[(size_t)b * NS * DD + idx];
        float lt = lat2[(size_t)b * NS * DD + idx];
        float ns = 0.6f * so + 0.4f * alpha[s] * tanhf(lt);
        stateNew[(size_t)b * NS * DD + idx] = ns;
        dout[4104 + b * NS * DD + idx] = ns;
    }
}

extern "C" void kernel_launch(void* const* d_in, const int* in_sizes, int n_in,
                              void* d_out, int out_size, void* d_ws, size_t ws_size,
                              hipStream_t stream)
{
    const float* x        = (const float*)d_in[0];
    const float* state0   = (const float*)d_in[1];
    const float* se_W     = (const float*)d_in[2];
    const float* se_b     = (const float*)d_in[3];
    const float* s_Wq     = (const float*)d_in[4];
    const float* s_bq     = (const float*)d_in[5];
    const float* s_Wk     = (const float*)d_in[6];
    const float* s_bk     = (const float*)d_in[7];
    const float* s_Wv     = (const float*)d_in[8];
    const float* s_bv     = (const float*)d_in[9];
    const float* s_Wo     = (const float*)d_in[10];
    const float* s_bo     = (const float*)d_in[11];
    const float* s_lnq_g  = (const float*)d_in[12];
    const float* s_lnq_b  = (const float*)d_in[13];
    const float* s_lnkv_g = (const float*)d_in[14];
    const float* s_lnkv_b = (const float*)d_in[15];
    const float* s_fc1_W  = (const float*)d_in[16];
    const float* s_fc1_b  = (const float*)d_in[17];
    const float* s_fc2_W  = (const float*)d_in[18];
    const float* s_fc2_b  = (const float*)d_in[19];
    const float* s_lnffn_g= (const float*)d_in[20];
    const float* s_lnffn_b= (const float*)d_in[21];
    const float* s_lnslot_g=(const float*)d_in[22];
    const float* s_lnslot_b=(const float*)d_in[23];
    const float* slot_ctx = (const float*)d_in[24];
    const float* oe_W     = (const float*)d_in[25];
    const float* oe_b     = (const float*)d_in[26];
    const float* o_Wq     = (const float*)d_in[27];
    const float* o_bq     = (const float*)d_in[28];
    const float* o_Wk     = (const float*)d_in[29];
    const float* o_bk     = (const float*)d_in[30];
    const float* o_Wv     = (const float*)d_in[31];
    const float* o_bv     = (const float*)d_in[32];
    const float* o_Wo     = (const float*)d_in[33];
    const float* o_bo     = (const float*)d_in[34];
    const float* o_lnq_g  = (const float*)d_in[35];
    const float* o_lnq_b  = (const float*)d_in[36];
    const float* o_lnkv_g = (const float*)d_in[37];
    const float* o_lnkv_b = (const float*)d_in[38];
    const float* o_fc1_W  = (const float*)d_in[39];
    const float* o_fc1_b  = (const float*)d_in[40];
    const float* o_fc2_W  = (const float*)d_in[41];
    const float* o_fc2_b  = (const float*)d_in[42];
    const float* o_lnffn_g= (const float*)d_in[43];
    const float* o_lnffn_b= (const float*)d_in[44];
    const float* op_W     = (const float*)d_in[45];
    const float* op_b     = (const float*)d_in[46];

    float* ws = (float*)d_ws;
    float* pe   = ws;
    float* cat  = ws + 1048576;
    bf16*  kh2  = (bf16*)(ws + 1048576);
    bf16*  vh2  = (bf16*)(ws + 1048576 + 2105344);
    bf16*  lnbb = (bf16*)(ws + 5259264);
    float* cat2 = ws + 7421952;
    bf16*  kh   = (bf16*)(ws + 7421952);
    bf16*  vh   = (bf16*)(ws + 7421952 + 2105344);
    bf16*  xb   = (bf16*)(ws + 11632640);
    bf16*  lnbb2= (bf16*)(ws + 11632640);
    bf16*  wb   = (bf16*)(ws + 13729792);
    bf16*  seWb = wb;
    bf16*  oeWb = wb + 1048576;
    bf16*  sWkb = wb + 2097152;
    bf16*  sWvb = wb + 3145728;
    bf16*  oWkb = wb + 4194304;
    bf16*  oWvb = wb + 5242880;
    float* sm   = ws + 16875520;
    float* qh_s    = sm + 16384;
    float* lat1    = sm + 49152;
    float* g1      = sm + 81920;
    float* lat2    = sm + 98304;
    float* q2h     = sm + 135232;
    float* lo_last = sm + 143424;
    float* lo1     = sm + 147520;
    float* g2      = sm + 155712;
    float* lo2     = sm + 159808;
    float* pmb     = sm + 163904;
    float* plb     = sm + 164928;
    float* paccb   = sm + 165952;
    float* stateNew= sm + 231488;
    float* out = (float*)d_out;

    dim3 blk(256);

    // ---- phase 0: conversions + PE + state-row copy ----
    PrepArgs pa;
    pa.cin[0] = x;    pa.cout[0] = xb;
    pa.cin[1] = se_W; pa.cout[1] = seWb;
    pa.cin[2] = oe_W; pa.cout[2] = oeWb;
    pa.cin[3] = s_Wk; pa.cout[3] = sWkb;
    pa.cin[4] = s_Wv; pa.cout[4] = sWvb;
    pa.cin[5] = o_Wk; pa.cout[5] = oWkb;
    pa.cin[6] = o_Wv; pa.cout[6] = oWvb;
    pa.state0 = state0; pa.cat = cat; pa.pe = pe;
    prep_kernel<<<11280, blk, 0, stream>>>(pa);

    // ---- phase 1: paired embeds (A shared), XCD-swizzled ----
    embed_pair_kernel<<<256, blk, 0, stream>>>(
        xb, seWb, oeWb, se_b, oe_b, cat, cat2, pe);

    // ---- phase 2: big LNs + q projections + lo_last (gate-independent) ----
    ln_fused_kernel<<<8208, blk, 0, stream>>>(cat, cat2, lnbb, lnbb2,
        s_lnkv_g, s_lnkv_b, o_lnkv_g, o_lnkv_b);
    lngemm_kernel<16><<<256, blk, 0, stream>>>(state0, 0, 1,
        s_lnq_g, s_lnq_b, s_Wq, s_bq, qh_s, 0);
    lngemm_kernel<4><<<256, blk, 0, stream>>>(cat2, TT - 1, LKV,
        o_lnq_g, o_lnq_b, o_Wq, o_bq, q2h, 0);
    copy_lolast_kernel<<<NB, blk, 0, stream>>>(cat2, lo_last);

    // ---- phase 3: paired K/V GEMMs (A shared), XCD-swizzled ----
    kv_pair_kernel<<<520, blk, 0, stream>>>(
        lnbb, lnbb2, sWkb, sWvb, oWkb, oWvb,
        s_bk, s_bv, o_bk, o_bv, kh, vh, kh2, vh2);

    // ---- phase 4: state-branch attention + slot MLP + gate ----
    attn_part_kernel<4><<<256, blk, 0, stream>>>(qh_s, kh, vh, pmb, plb, paccb);
    comb_gemm_kernel<4><<<256, blk, 0, stream>>>(pmb, plb, paccb,
        s_Wo, s_bo, state0, lat1);
    lngemm_kernel<16><<<256, blk, 0, stream>>>(lat1, 0, 1,
        s_lnffn_g, s_lnffn_b, s_fc1_W, s_fc1_b, g1, 1);
    plaingemm_kernel<16><<<256, blk, 0, stream>>>(g1, s_fc2_W, s_fc2_b, lat1, lat2, 0);
    gate_fused_kernel<<<NB, blk, 0, stream>>>(lat2, s_lnslot_g, s_lnslot_b,
        slot_ctx, state0, stateNew, out);

    // ---- phase 5: new-state K/V rows (paired) ----
    kvpair_rows_kernel<<<256, blk, 0, stream>>>(stateNew,
        o_lnkv_g, o_lnkv_b, o_Wk, o_bk, o_Wv, o_bv, kh2, vh2);

    // ---- phase 6: out-branch attention (last token) + head ----
    attn_part_kernel<1><<<256, blk, 0, stream>>>(q2h, kh2, vh2, pmb, plb, paccb);
    comb_gemm_kernel<1><<<256, blk, 0, stream>>>(pmb, plb, paccb,
        o_Wo, o_bo, lo_last, lo1);
    lngemm_kernel<4><<<256, blk, 0, stream>>>(lo1, 0, 1,
        o_lnffn_g, o_lnffn_b, o_fc1_W, o_fc1_b, g2, 1);
    plaingemm_kernel<4><<<256, blk, 0, stream>>>(g2, o_fc2_W, o_fc2_b, lo1, lo2, 0);
    plaingemm_kernel<4><<<256, blk, 0, stream>>>(lo2, op_W, op_b, nullptr, out, 0);
}

// Round 12
// 313.805 us; speedup vs baseline: 1.1706x; 1.1706x over previous
//
#include <hip/hip_runtime.h>
#include <hip/hip_bf16.h>

#define DD 1024
#define NB 4
#define TT 1024
#define NH 16
#define NS 4
#define LKV 1028   // NS + TT
#define NCH 4
#define CHS 257    // keys per chunk (4*257 = 1028)

typedef __hip_bfloat16 bf16;
typedef __attribute__((ext_vector_type(8))) short short8;
typedef __attribute__((ext_vector_type(4))) float f32x4;

#define GLD16(gp, lp) __builtin_amdgcn_global_load_lds( \
    (const __attribute__((address_space(1))) unsigned int*)(const void*)(gp), \
    (__attribute__((address_space(3))) unsigned int*)(void*)(lp), 16, 0, 0)

__device__ __forceinline__ float warp_sum(float v) {
#pragma unroll
    for (int o = 32; o > 0; o >>= 1) v += __shfl_xor(v, o);
    return v;
}

__device__ __forceinline__ float b2f(unsigned short u) {
    union { unsigned int i; float f; } x; x.i = ((unsigned)u) << 16; return x.f;
}
__device__ __forceinline__ unsigned short f2b(float f) {
    bf16 h = __float2bfloat16(f);
    union { bf16 h; unsigned short u; } x; x.h = h; return x.u;
}

// ================= prep: cvt x + 6 weights, PE table, state copy ==============
struct PrepArgs {
    const float* cin[7];   // x, seW, oeW, sWk, sWv, oWk, oWv
    bf16* cout[7];
    const float* state0;
    float* cat;
    float* pe;
};

__global__ __launch_bounds__(256) void prep_kernel(PrepArgs a) {
    int bid = blockIdx.x;
    int tid = threadIdx.x;
    if (bid < 10240) {
        const float* in; bf16* out; size_t off;
        if (bid < 4096) { in = a.cin[0]; out = a.cout[0]; off = (size_t)bid * 1024; }
        else {
            int w = (bid - 4096) >> 10;
            in = a.cin[1 + w]; out = a.cout[1 + w];
            off = (size_t)((bid - 4096) & 1023) * 1024;
        }
        size_t i = off + tid * 4;
        float4 v = *(const float4*)(in + i);
        out[i + 0] = __float2bfloat16(v.x);
        out[i + 1] = __float2bfloat16(v.y);
        out[i + 2] = __float2bfloat16(v.z);
        out[i + 3] = __float2bfloat16(v.w);
    } else if (bid < 11264) {
        int t = bid - 10240;
#pragma unroll
        for (int i = 0; i < 2; ++i) {
            int j = i * 256 + tid;                       // 0..511
            float ang = (float)t * exp2f(-(float)j * (1.0f / 256.0f));
            a.pe[(size_t)t * DD + j]       = sinf(ang);
            a.pe[(size_t)t * DD + 512 + j] = cosf(ang);
        }
    } else {
        int r = bid - 11264;       // 0..15
        int b = r >> 2, s = r & 3;
#pragma unroll
        for (int i = 0; i < 4; ++i)
            a.cat[(size_t)(b * LKV + s) * DD + i * 256 + tid] =
                a.state0[(size_t)r * DD + i * 256 + tid];
    }
}

// ================= fused LayerNorm -> bf16 (state-kv rows + out token rows) ===
__global__ __launch_bounds__(256) void ln_fused_kernel(
    const float* __restrict__ cat, const float* __restrict__ cat2,
    bf16* __restrict__ lnbb, bf16* __restrict__ lnbb2,
    const float* __restrict__ sg, const float* __restrict__ sb,
    const float* __restrict__ og, const float* __restrict__ ob)
{
    int bid = blockIdx.x;
    int tid = threadIdx.x;
    const float* in; bf16* out; const float* g; const float* b;
    if (bid < 4112) {
        in = cat + (size_t)bid * DD; out = lnbb + (size_t)bid * DD; g = sg; b = sb;
    } else {
        int r = bid - 4112;
        int row = (r >> 10) * LKV + (r & 1023);
        in = cat2 + (size_t)row * DD; out = lnbb2 + (size_t)r * DD; g = og; b = ob;
    }
    float v[4];
    float s1 = 0.f, s2 = 0.f;
#pragma unroll
    for (int i = 0; i < 4; ++i) {
        v[i] = in[i * 256 + tid];
        s1 += v[i]; s2 += v[i] * v[i];
    }
    s1 = warp_sum(s1); s2 = warp_sum(s2);
    __shared__ float a1[4], a2[4];
    int w = tid >> 6;
    if ((tid & 63) == 0) { a1[w] = s1; a2[w] = s2; }
    __syncthreads();
    s1 = a1[0] + a1[1] + a1[2] + a1[3];
    s2 = a2[0] + a2[1] + a2[2] + a2[3];
    float mu  = s1 * (1.0f / DD);
    float var = s2 * (1.0f / DD) - mu * mu;
    var = var < 0.f ? 0.f : var;
    float rs = rsqrtf(var + 1e-5f);
#pragma unroll
    for (int i = 0; i < 4; ++i) {
        int c = i * 256 + tid;
        out[c] = __float2bfloat16((v[i] - mu) * rs * g[c] + b[c]);
    }
}

// ================= MFMA tile body (128x128, BK=32, 4 waves, VGPR ~76) =========
__device__ __forceinline__ void mfma_tile(
    const bf16* __restrict__ A, const bf16* __restrict__ W,
    const float* __restrict__ bias,
    float* __restrict__ outf, bf16* __restrict__ outb,
    int M, int obs, int oro, const float* __restrict__ pe,
    bf16* As, bf16* Ws, int m0, int n0)
{
    int tid  = threadIdx.x;
    int lane = tid & 63;
    int wave = tid >> 6;
    int wm = (wave >> 1) << 6;
    int wn = (wave & 1) << 6;

    f32x4 acc[4][4] = {};

    int soff  = wave * 1024 + lane * 16;
    int srow  = soff >> 6;
    int scol  = (soff & 63) >> 1;
    char* lA0 = (char*)As + wave * 1024;
    char* lA1 = (char*)As + 4096 + wave * 1024;
    char* lW0 = (char*)Ws + wave * 1024;
    char* lW1 = (char*)Ws + 4096 + wave * 1024;

    int fRow = lane & 15;
    int kOff = (lane >> 4) << 3;

    for (int k0 = 0; k0 < DD; k0 += 32) {
        GLD16(A + (size_t)(m0 + srow) * DD + k0 + scol,      lA0);
        GLD16(A + (size_t)(m0 + 64 + srow) * DD + k0 + scol, lA1);
        GLD16(W + (size_t)(n0 + srow) * DD + k0 + scol,      lW0);
        GLD16(W + (size_t)(n0 + 64 + srow) * DD + k0 + scol, lW1);
        __syncthreads();
        short8 a[4], b[4];
#pragma unroll
        for (int mi = 0; mi < 4; ++mi)
            a[mi] = *(const short8*)(As + (wm + mi * 16 + fRow) * 32 + kOff);
#pragma unroll
        for (int ni = 0; ni < 4; ++ni)
            b[ni] = *(const short8*)(Ws + (wn + ni * 16 + fRow) * 32 + kOff);
#pragma unroll
        for (int mi = 0; mi < 4; ++mi)
#pragma unroll
            for (int ni = 0; ni < 4; ++ni)
                acc[mi][ni] = __builtin_amdgcn_mfma_f32_16x16x32_bf16(
                    a[mi], b[ni], acc[mi][ni], 0, 0, 0);
        __syncthreads();
    }

    int cCol  = lane & 15;
    int cRow4 = (lane >> 4) << 2;
#pragma unroll
    for (int mi = 0; mi < 4; ++mi) {
#pragma unroll
        for (int ni = 0; ni < 4; ++ni) {
#pragma unroll
            for (int r = 0; r < 4; ++r) {
                int row = m0 + wm + mi * 16 + cRow4 + r;
                int col = n0 + wn + ni * 16 + cCol;
                if (row < M) {
                    float v = acc[mi][ni][r] + bias[col];
                    if (outf) {
                        v += pe[(size_t)(row & 1023) * DD + col];
                        int orow = (row >> 10) * obs + oro + (row & 1023);
                        outf[(size_t)orow * DD + col] = v;
                    } else {
                        int orow = obs ? ((row >> 10) * obs + (row & 1023)) : row;
                        outb[(size_t)orow * DD + col] = __float2bfloat16(v);
                    }
                }
            }
        }
    }
}

// ================= fused embeds, XCD-swizzled linear grid (512 blocks) ========
__global__ __launch_bounds__(256) void embed_fused_kernel(
    const bf16* __restrict__ xb,
    const bf16* __restrict__ seW, const bf16* __restrict__ oeW,
    const float* __restrict__ seb, const float* __restrict__ oeb,
    float* __restrict__ cat, float* __restrict__ cat2,
    const float* __restrict__ pe)
{
    __shared__ bf16 As[128 * 32];
    __shared__ bf16 Ws[128 * 32];
    int bid = blockIdx.x;
    int t = (bid & 7) * 64 + (bid >> 3);   // bijective XCD swizzle (512 = 8*64)
    int x = t & 7;
    int q = t >> 3;
    int z = q & 1;
    int y = q >> 1;
    const bf16* W = z ? oeW : seW;
    const float* bias = z ? oeb : seb;
    float* outf = z ? cat2 : cat;
    int oro = z ? 0 : NS;
    mfma_tile(xb, W, bias, outf, nullptr, 4096, LKV, oro, pe, As, Ws,
              y * 128, x * 128);
}

// ================= fused K/V GEMMs, XCD-swizzled linear grid (1056 blocks) ====
__global__ __launch_bounds__(256) void kv_fused_kernel(
    const bf16* __restrict__ lnbb, const bf16* __restrict__ lnbb2,
    const bf16* __restrict__ W0, const bf16* __restrict__ W1,
    const bf16* __restrict__ W2, const bf16* __restrict__ W3,
    const float* __restrict__ b0, const float* __restrict__ b1,
    const float* __restrict__ b2, const float* __restrict__ b3,
    bf16* __restrict__ o0, bf16* __restrict__ o1,
    bf16* __restrict__ o2, bf16* __restrict__ o3)
{
    __shared__ bf16 As[128 * 32];
    __shared__ bf16 Ws[128 * 32];
    int bid = blockIdx.x;
    int t = (bid & 7) * 132 + (bid >> 3);  // bijective XCD swizzle (1056 = 8*132)
    int x = t & 7;
    int u = t >> 3;          // 0..131
    int zi = u & 1;
    int v = u >> 1;          // 0..65
    int y = v % 33;
    int zp = v / 33;
    int z = zp * 2 + zi;
    const bf16* Warr[4] = {W0, W1, W2, W3};
    const float* barr[4] = {b0, b1, b2, b3};
    bf16* oarr[4] = {o0, o1, o2, o3};
    const bf16* A = (zp == 0) ? lnbb : lnbb2;
    int M   = (zp == 0) ? 4112 : 4096;
    int obs = (zp == 0) ? 0 : LKV;
    mfma_tile(A, Warr[z], barr[z], nullptr, oarr[z], M, obs, 0, nullptr, As, Ws,
              y * 128, x * 128);
}

// ================= copy lo[:, -1] =============================================
__global__ __launch_bounds__(256) void copy_lolast_kernel(
    const float* __restrict__ cat2, float* __restrict__ dst)
{
    int b = blockIdx.x;
    int tid = threadIdx.x;
#pragma unroll
    for (int i = 0; i < 4; ++i)
        dst[(size_t)b * DD + i * 256 + tid] =
            cat2[(size_t)(b * LKV + (TT - 1)) * DD + i * 256 + tid];
}

// ================= small-op device stages (mega-validated) ====================
template<int M>
__device__ void stage_rows_ln_bf16(
    const float* A, int row0, int rstride,
    const float* lng, const float* lnb,
    bf16* Asb, float* part1, float* part2)
{
    int tid = threadIdx.x, lane = tid & 63, w = tid >> 6;
#pragma unroll
    for (int i = 0; i < M; ++i) {
        const float* row = A + (size_t)(row0 + i * rstride) * DD;
        float4 v = *(const float4*)(row + tid * 4);
        float s1 = v.x + v.y + v.z + v.w;
        float s2 = v.x*v.x + v.y*v.y + v.z*v.z + v.w*v.w;
        s1 = warp_sum(s1); s2 = warp_sum(s2);
        if (lane == 0) { part1[i * 4 + w] = s1; part2[i * 4 + w] = s2; }
    }
    __syncthreads();
    float4 gv = *(const float4*)(lng + tid * 4);
    float4 bv = *(const float4*)(lnb + tid * 4);
#pragma unroll
    for (int i = 0; i < M; ++i) {
        float s1 = part1[i*4+0] + part1[i*4+1] + part1[i*4+2] + part1[i*4+3];
        float s2 = part2[i*4+0] + part2[i*4+1] + part2[i*4+2] + part2[i*4+3];
        float mu = s1 * (1.0f / DD);
        float var = s2 * (1.0f / DD) - mu * mu;
        var = var < 0.f ? 0.f : var;
        float rs = rsqrtf(var + 1e-5f);
        const float* row = A + (size_t)(row0 + i * rstride) * DD;
        float4 v = *(const float4*)(row + tid * 4);
        ushort4 o;
        o.x = f2b((v.x - mu) * rs * gv.x + bv.x);
        o.y = f2b((v.y - mu) * rs * gv.y + bv.y);
        o.z = f2b((v.z - mu) * rs * gv.z + bv.z);
        o.w = f2b((v.w - mu) * rs * gv.w + bv.w);
        *(ushort4*)(Asb + i * DD + tid * 4) = o;
    }
    __syncthreads();
}

template<int M>
__device__ void stage_rows_plain_bf16(const float* A, bf16* Asb)
{
    int tid = threadIdx.x;
#pragma unroll
    for (int i = 0; i < M; ++i) {
        float4 v = *(const float4*)(A + (size_t)i * DD + tid * 4);
        ushort4 o;
        o.x = f2b(v.x); o.y = f2b(v.y); o.z = f2b(v.z); o.w = f2b(v.w);
        *(ushort4*)(Asb + i * DD + tid * 4) = o;
    }
    __syncthreads();
}

template<int LQ>
__device__ void stage_combine(const float* pm, const float* pl,
                              const float* pacc, bf16* Asb)
{
    int tid = threadIdx.x;
    for (int idx = tid; idx < LQ * 4 * 256; idx += 256) {
        int m  = idx >> 8;
        int n4 = (idx & 255) * 4;
        int b = m / LQ, qi = m - b * LQ;
        int h = n4 >> 6, d = n4 & 63;
        int base = ((b * 16 + h) * 4 + qi) * NCH;
        float m0 = pm[base], m1 = pm[base+1], m2 = pm[base+2], m3 = pm[base+3];
        float Mx = fmaxf(fmaxf(m0, m1), fmaxf(m2, m3));
        float w0 = expf(m0-Mx), w1 = expf(m1-Mx), w2 = expf(m2-Mx), w3 = expf(m3-Mx);
        float L = pl[base]*w0 + pl[base+1]*w1 + pl[base+2]*w2 + pl[base+3]*w3;
        float inv = 1.f / L;
        float4 a0 = *(const float4*)(pacc + (size_t)(base+0)*64 + d);
        float4 a1 = *(const float4*)(pacc + (size_t)(base+1)*64 + d);
        float4 a2 = *(const float4*)(pacc + (size_t)(base+2)*64 + d);
        float4 a3 = *(const float4*)(pacc + (size_t)(base+3)*64 + d);
        ushort4 o;
        o.x = f2b((a0.x*w0 + a1.x*w1 + a2.x*w2 + a3.x*w3) * inv);
        o.y = f2b((a0.y*w0 + a1.y*w1 + a2.y*w2 + a3.y*w3) * inv);
        o.z = f2b((a0.z*w0 + a1.z*w1 + a2.z*w2 + a3.z*w3) * inv);
        o.w = f2b((a0.w*w0 + a1.w*w1 + a2.w*w2 + a3.w*w3) * inv);
        *(ushort4*)(Asb + m * DD + n4) = o;
    }
    __syncthreads();
}

template<int M>
__device__ void gemm_stage(const bf16* Asb, const float* W, const float* bias,
                           float* outf, const float* res, int gelu, int n)
{
    int lane = threadIdx.x & 63;
    const float* Wr = W + (size_t)n * DD;
    float acc[M] = {};
#pragma unroll
    for (int j = 0; j < 4; ++j) {
        float4 wv = *(const float4*)(Wr + j * 256 + lane * 4);
#pragma unroll
        for (int m = 0; m < M; ++m) {
            ushort4 av = *(const ushort4*)(Asb + m * DD + j * 256 + lane * 4);
            acc[m] += b2f(av.x)*wv.x + b2f(av.y)*wv.y
                    + b2f(av.z)*wv.z + b2f(av.w)*wv.w;
        }
    }
#pragma unroll
    for (int m = 0; m < M; ++m) acc[m] = warp_sum(acc[m]);
    if (lane == 0) {
#pragma unroll
        for (int m = 0; m < M; ++m) {
            float v = acc[m] + bias[n];
            if (gelu) v = 0.5f * v * (1.0f + erff(v * 0.70710678118654752f));
            if (res)  v += res[(size_t)m * DD + n];
            outf[(size_t)m * DD + n] = v;
        }
    }
}

// ================= small-op kernel wrappers ===================================
template<int M>
__global__ __launch_bounds__(256) void lngemm_kernel(
    const float* __restrict__ A, int row0, int rstride,
    const float* __restrict__ lng, const float* __restrict__ lnb,
    const float* __restrict__ W, const float* __restrict__ bias,
    float* __restrict__ outf, int gelu)
{
    __shared__ bf16 Asb[M * DD];
    __shared__ float part1[64], part2[64];
    stage_rows_ln_bf16<M>(A, row0, rstride, lng, lnb, Asb, part1, part2);
    gemm_stage<M>(Asb, W, bias, outf, nullptr, gelu, blockIdx.x * 4 + (threadIdx.x >> 6));
}

template<int M>
__global__ __launch_bounds__(256) void plaingemm_kernel(
    const float* __restrict__ A,
    const float* __restrict__ W, const float* __restrict__ bias,
    const float* __restrict__ res, float* __restrict__ outf, int gelu)
{
    __shared__ bf16 Asb[M * DD];
    stage_rows_plain_bf16<M>(A, Asb);
    gemm_stage<M>(Asb, W, bias, outf, res, gelu, blockIdx.x * 4 + (threadIdx.x >> 6));
}

template<int LQ>
__global__ __launch_bounds__(256) void comb_gemm_kernel(
    const float* __restrict__ pm, const float* __restrict__ pl,
    const float* __restrict__ pacc,
    const float* __restrict__ W, const float* __restrict__ bias,
    const float* __restrict__ res, float* __restrict__ outf)
{
    __shared__ bf16 Asb[LQ * 4 * DD];
    stage_combine<LQ>(pm, pl, pacc, Asb);
    gemm_stage<LQ * 4>(Asb, W, bias, outf, res, 0, blockIdx.x * 4 + (threadIdx.x >> 6));
}

// LN(stateNew) -> paired K,V state-row projections into kh2/vh2 (remapped rows)
__global__ __launch_bounds__(256) void kvpair_rows_kernel(
    const float* __restrict__ stateNew,
    const float* __restrict__ lng, const float* __restrict__ lnb,
    const float* __restrict__ Wk, const float* __restrict__ bk,
    const float* __restrict__ Wv, const float* __restrict__ bv,
    bf16* __restrict__ kh2, bf16* __restrict__ vh2)
{
    __shared__ bf16 Asb[16 * DD];
    __shared__ float part1[64], part2[64];
    stage_rows_ln_bf16<16>(stateNew, 0, 1, lng, lnb, Asb, part1, part2);
    int lane = threadIdx.x & 63;
    int n = blockIdx.x * 4 + (threadIdx.x >> 6);
    const float* WrK = Wk + (size_t)n * DD;
    const float* WrV = Wv + (size_t)n * DD;
    float accK[16] = {}, accV[16] = {};
#pragma unroll
    for (int j = 0; j < 4; ++j) {
        float4 wk4 = *(const float4*)(WrK + j * 256 + lane * 4);
        float4 wv4 = *(const float4*)(WrV + j * 256 + lane * 4);
#pragma unroll
        for (int m = 0; m < 16; ++m) {
            ushort4 av = *(const ushort4*)(Asb + m * DD + j * 256 + lane * 4);
            float ax = b2f(av.x), ay = b2f(av.y), az = b2f(av.z), aw = b2f(av.w);
            accK[m] += ax*wk4.x + ay*wk4.y + az*wk4.z + aw*wk4.w;
            accV[m] += ax*wv4.x + ay*wv4.y + az*wv4.z + aw*wv4.w;
        }
    }
#pragma unroll
    for (int m = 0; m < 16; ++m) { accK[m] = warp_sum(accK[m]); accV[m] = warp_sum(accV[m]); }
    if (lane == 0) {
#pragma unroll
        for (int m = 0; m < 16; ++m) {
            int orow = (m >> 2) * LKV + TT + (m & 3);
            kh2[(size_t)orow * DD + n] = __float2bfloat16(accK[m] + bk[n]);
            vh2[(size_t)orow * DD + n] = __float2bfloat16(accV[m] + bv[n]);
        }
    }
}

// ================= split-K flash-decode attention =============================
template<int LQ>
__global__ __launch_bounds__(256) void attn_part_kernel(
    const float* __restrict__ qh, const bf16* __restrict__ kh,
    const bf16* __restrict__ vh, float* __restrict__ pm,
    float* __restrict__ pl, float* __restrict__ pacc)
{
    int blk = blockIdx.x;
    int c  = blk & (NCH - 1);
    int bh = blk >> 2;
    int b = bh >> 4, h = bh & 15;
    int tid = threadIdx.x;
    int lane = tid & 63, w = tid >> 6;

    __shared__ float qs[LQ][64];
    __shared__ float sc[LQ][CHS];
    __shared__ float redm[4][LQ];
    __shared__ float redl[4][LQ];
    __shared__ float paccs[4][LQ][64];

    if (w < LQ) qs[w][lane] = qh[(size_t)(b * LQ + w) * DD + h * 64 + lane];
    __syncthreads();

    int kbeg = c * CHS;
    for (int t = tid; t < CHS; t += 256) {
        const ushort4* kr = (const ushort4*)((const unsigned short*)kh
            + (size_t)(b * LKV + kbeg + t) * DD + h * 64);
        float kf[64];
#pragma unroll
        for (int i = 0; i < 16; ++i) {
            ushort4 kk = kr[i];
            kf[i*4+0] = b2f(kk.x); kf[i*4+1] = b2f(kk.y);
            kf[i*4+2] = b2f(kk.z); kf[i*4+3] = b2f(kk.w);
        }
#pragma unroll
        for (int qi = 0; qi < LQ; ++qi) {
            float s = 0.f;
#pragma unroll
            for (int d = 0; d < 64; ++d) s += qs[qi][d] * kf[d];
            sc[qi][t] = s * 0.125f;
        }
    }
    __syncthreads();

    float M[LQ], L[LQ];
#pragma unroll
    for (int qi = 0; qi < LQ; ++qi) {
        float lm = -1e30f;
        for (int t = tid; t < CHS; t += 256) lm = fmaxf(lm, sc[qi][t]);
#pragma unroll
        for (int o = 32; o > 0; o >>= 1) lm = fmaxf(lm, __shfl_xor(lm, o));
        if (lane == 0) redm[w][qi] = lm;
    }
    __syncthreads();
#pragma unroll
    for (int qi = 0; qi < LQ; ++qi)
        M[qi] = fmaxf(fmaxf(redm[0][qi], redm[1][qi]), fmaxf(redm[2][qi], redm[3][qi]));

#pragma unroll
    for (int qi = 0; qi < LQ; ++qi) {
        float ls = 0.f;
        for (int t = tid; t < CHS; t += 256) {
            float e = expf(sc[qi][t] - M[qi]);
            sc[qi][t] = e;
            ls += e;
        }
        ls = warp_sum(ls);
        if (lane == 0) redl[w][qi] = ls;
    }
    __syncthreads();
#pragma unroll
    for (int qi = 0; qi < LQ; ++qi)
        L[qi] = redl[0][qi] + redl[1][qi] + redl[2][qi] + redl[3][qi];

    {
        int k0 = w * 65;
        int k1 = (k0 + 65 < CHS) ? k0 + 65 : CHS;
        float acc[LQ] = {};
        const unsigned short* vb = (const unsigned short*)vh
            + (size_t)(b * LKV + kbeg) * DD + h * 64 + lane;
        for (int k = k0; k < k1; ++k) {
            float v = b2f(vb[(size_t)k * DD]);
#pragma unroll
            for (int qi = 0; qi < LQ; ++qi) acc[qi] += sc[qi][k] * v;
        }
#pragma unroll
        for (int qi = 0; qi < LQ; ++qi) paccs[w][qi][lane] = acc[qi];
    }
    __syncthreads();
    if (tid < 64) {
#pragma unroll
        for (int qi = 0; qi < LQ; ++qi) {
            float s = paccs[0][qi][tid] + paccs[1][qi][tid]
                    + paccs[2][qi][tid] + paccs[3][qi][tid];
            pacc[(size_t)((bh * 4 + qi) * NCH + c) * 64 + tid] = s;
        }
    }
    if (tid < LQ) {
        pm[(bh * 4 + tid) * NCH + c] = M[tid];
        pl[(bh * 4 + tid) * NCH + c] = L[tid];
    }
}

// ========== fused gate: LN(lat2) -> logits -> top2 -> state update ============
__global__ __launch_bounds__(256) void gate_fused_kernel(
    const float* __restrict__ lat2,
    const float* __restrict__ lng, const float* __restrict__ lnb,
    const float* __restrict__ ctx,
    const float* __restrict__ state_old, float* __restrict__ stateNew,
    float* __restrict__ dout)
{
    int b = blockIdx.x;
    int tid = threadIdx.x;
    int lane = tid & 63, w = tid >> 6;
    __shared__ float logit[NS];
    __shared__ float alpha[NS];

    {
        const float* row = lat2 + (size_t)(b * NS + w) * DD;
        float4 v[4];
        float s1 = 0.f, s2 = 0.f;
#pragma unroll
        for (int j = 0; j < 4; ++j) {
            v[j] = *(const float4*)(row + (j * 64 + lane) * 4);
            s1 += v[j].x + v[j].y + v[j].z + v[j].w;
            s2 += v[j].x*v[j].x + v[j].y*v[j].y + v[j].z*v[j].z + v[j].w*v[j].w;
        }
        s1 = warp_sum(s1); s2 = warp_sum(s2);
        float mu = s1 * (1.0f / DD);
        float var = s2 * (1.0f / DD) - mu * mu;
        var = var < 0.f ? 0.f : var;
        float rs = rsqrtf(var + 1e-5f);
        float dot = 0.f;
#pragma unroll
        for (int j = 0; j < 4; ++j) {
            int c = (j * 64 + lane) * 4;
            float4 gv = *(const float4*)(lng + c);
            float4 bv = *(const float4*)(lnb + c);
            float4 cv = *(const float4*)(ctx + c);
            dot += ((v[j].x - mu) * rs * gv.x + bv.x) * cv.x
                 + ((v[j].y - mu) * rs * gv.y + bv.y) * cv.y
                 + ((v[j].z - mu) * rs * gv.z + bv.z) * cv.z
                 + ((v[j].w - mu) * rs * gv.w + bv.w) * cv.w;
        }
        dot = warp_sum(dot);
        if (lane == 0) logit[w] = dot;
    }
    __syncthreads();
    if (tid == 0) {
        float l[NS];
        for (int s = 0; s < NS; ++s) l[s] = logit[s];
        int i0 = 0;
        for (int s = 1; s < NS; ++s) if (l[s] > l[i0]) i0 = s;
        int i1 = (i0 == 0) ? 1 : 0;
        for (int s = 0; s < NS; ++s) if (s != i0 && l[s] > l[i1]) i1 = s;
        float mx = fmaxf(l[i0], l[i1]);
        float e0 = expf(l[i0] - mx), e1 = expf(l[i1] - mx);
        float inv = 1.f / (e0 + e1);
        for (int s = 0; s < NS; ++s) alpha[s] = 0.f;
        alpha[i0] = e0 * inv;
        alpha[i1] += e1 * inv;
        dout[4096 + b * 2 + 0] = (float)i0;
        dout[4096 + b * 2 + 1] = (float)i1;
    }
    __syncthreads();
    for (int idx = tid; idx < NS * DD; idx += 256) {
        int s = idx >> 10;
        float so = state_old[(size_t)b * NS * DD + idx];
        float lt = lat2[(size_t)b * NS * DD + idx];
        float ns = 0.6f * so + 0.4f * alpha[s] * tanhf(lt);
        stateNew[(size_t)b * NS * DD + idx] = ns;
        dout[4104 + b * NS * DD + idx] = ns;
    }
}

extern "C" void kernel_launch(void* const* d_in, const int* in_sizes, int n_in,
                              void* d_out, int out_size, void* d_ws, size_t ws_size,
                              hipStream_t stream)
{
    const float* x        = (const float*)d_in[0];
    const float* state0   = (const float*)d_in[1];
    const float* se_W     = (const float*)d_in[2];
    const float* se_b     = (const float*)d_in[3];
    const float* s_Wq     = (const float*)d_in[4];
    const float* s_bq     = (const float*)d_in[5];
    const float* s_Wk     = (const float*)d_in[6];
    const float* s_bk     = (const float*)d_in[7];
    const float* s_Wv     = (const float*)d_in[8];
    const float* s_bv     = (const float*)d_in[9];
    const float* s_Wo     = (const float*)d_in[10];
    const float* s_bo     = (const float*)d_in[11];
    const float* s_lnq_g  = (const float*)d_in[12];
    const float* s_lnq_b  = (const float*)d_in[13];
    const float* s_lnkv_g = (const float*)d_in[14];
    const float* s_lnkv_b = (const float*)d_in[15];
    const float* s_fc1_W  = (const float*)d_in[16];
    const float* s_fc1_b  = (const float*)d_in[17];
    const float* s_fc2_W  = (const float*)d_in[18];
    const float* s_fc2_b  = (const float*)d_in[19];
    const float* s_lnffn_g= (const float*)d_in[20];
    const float* s_lnffn_b= (const float*)d_in[21];
    const float* s_lnslot_g=(const float*)d_in[22];
    const float* s_lnslot_b=(const float*)d_in[23];
    const float* slot_ctx = (const float*)d_in[24];
    const float* oe_W     = (const float*)d_in[25];
    const float* oe_b     = (const float*)d_in[26];
    const float* o_Wq     = (const float*)d_in[27];
    const float* o_bq     = (const float*)d_in[28];
    const float* o_Wk     = (const float*)d_in[29];
    const float* o_bk     = (const float*)d_in[30];
    const float* o_Wv     = (const float*)d_in[31];
    const float* o_bv     = (const float*)d_in[32];
    const float* o_Wo     = (const float*)d_in[33];
    const float* o_bo     = (const float*)d_in[34];
    const float* o_lnq_g  = (const float*)d_in[35];
    const float* o_lnq_b  = (const float*)d_in[36];
    const float* o_lnkv_g = (const float*)d_in[37];
    const float* o_lnkv_b = (const float*)d_in[38];
    const float* o_fc1_W  = (const float*)d_in[39];
    const float* o_fc1_b  = (const float*)d_in[40];
    const float* o_fc2_W  = (const float*)d_in[41];
    const float* o_fc2_b  = (const float*)d_in[42];
    const float* o_lnffn_g= (const float*)d_in[43];
    const float* o_lnffn_b= (const float*)d_in[44];
    const float* op_W     = (const float*)d_in[45];
    const float* op_b     = (const float*)d_in[46];

    float* ws = (float*)d_ws;
    float* pe   = ws;
    float* cat  = ws + 1048576;
    bf16*  kh2  = (bf16*)(ws + 1048576);
    bf16*  vh2  = (bf16*)(ws + 1048576 + 2105344);
    bf16*  lnbb = (bf16*)(ws + 5259264);
    float* cat2 = ws + 7421952;
    bf16*  kh   = (bf16*)(ws + 7421952);
    bf16*  vh   = (bf16*)(ws + 7421952 + 2105344);
    bf16*  xb   = (bf16*)(ws + 11632640);
    bf16*  lnbb2= (bf16*)(ws + 11632640);
    bf16*  wb   = (bf16*)(ws + 13729792);
    bf16*  seWb = wb;
    bf16*  oeWb = wb + 1048576;
    bf16*  sWkb = wb + 2097152;
    bf16*  sWvb = wb + 3145728;
    bf16*  oWkb = wb + 4194304;
    bf16*  oWvb = wb + 5242880;
    float* sm   = ws + 16875520;
    float* qh_s    = sm + 16384;
    float* lat1    = sm + 49152;
    float* g1      = sm + 81920;
    float* lat2    = sm + 98304;
    float* q2h     = sm + 135232;
    float* lo_last = sm + 143424;
    float* lo1     = sm + 147520;
    float* g2      = sm + 155712;
    float* lo2     = sm + 159808;
    float* pmb     = sm + 163904;
    float* plb     = sm + 164928;
    float* paccb   = sm + 165952;
    float* stateNew= sm + 231488;
    float* out = (float*)d_out;

    dim3 blk(256);

    // ---- phase 0: conversions + PE + state-row copy ----
    PrepArgs pa;
    pa.cin[0] = x;    pa.cout[0] = xb;
    pa.cin[1] = se_W; pa.cout[1] = seWb;
    pa.cin[2] = oe_W; pa.cout[2] = oeWb;
    pa.cin[3] = s_Wk; pa.cout[3] = sWkb;
    pa.cin[4] = s_Wv; pa.cout[4] = sWvb;
    pa.cin[5] = o_Wk; pa.cout[5] = oWkb;
    pa.cin[6] = o_Wv; pa.cout[6] = oWvb;
    pa.state0 = state0; pa.cat = cat; pa.pe = pe;
    prep_kernel<<<11280, blk, 0, stream>>>(pa);

    // ---- phase 1: both embeds (1 GEMM/block, high occupancy), XCD-swizzled ----
    embed_fused_kernel<<<512, blk, 0, stream>>>(
        xb, seWb, oeWb, se_b, oe_b, cat, cat2, pe);

    // ---- phase 2: big LNs + q projections + lo_last (gate-independent) ----
    ln_fused_kernel<<<8208, blk, 0, stream>>>(cat, cat2, lnbb, lnbb2,
        s_lnkv_g, s_lnkv_b, o_lnkv_g, o_lnkv_b);
    lngemm_kernel<16><<<256, blk, 0, stream>>>(state0, 0, 1,
        s_lnq_g, s_lnq_b, s_Wq, s_bq, qh_s, 0);
    lngemm_kernel<4><<<256, blk, 0, stream>>>(cat2, TT - 1, LKV,
        o_lnq_g, o_lnq_b, o_Wq, o_bq, q2h, 0);
    copy_lolast_kernel<<<NB, blk, 0, stream>>>(cat2, lo_last);

    // ---- phase 3: four K/V GEMMs (1 GEMM/block), XCD-swizzled ----
    kv_fused_kernel<<<1056, blk, 0, stream>>>(
        lnbb, lnbb2, sWkb, sWvb, oWkb, oWvb,
        s_bk, s_bv, o_bk, o_bv, kh, vh, kh2, vh2);

    // ---- phase 4: state-branch attention + slot MLP + gate ----
    attn_part_kernel<4><<<256, blk, 0, stream>>>(qh_s, kh, vh, pmb, plb, paccb);
    comb_gemm_kernel<4><<<256, blk, 0, stream>>>(pmb, plb, paccb,
        s_Wo, s_bo, state0, lat1);
    lngemm_kernel<16><<<256, blk, 0, stream>>>(lat1, 0, 1,
        s_lnffn_g, s_lnffn_b, s_fc1_W, s_fc1_b, g1, 1);
    plaingemm_kernel<16><<<256, blk, 0, stream>>>(g1, s_fc2_W, s_fc2_b, lat1, lat2, 0);
    gate_fused_kernel<<<NB, blk, 0, stream>>>(lat2, s_lnslot_g, s_lnslot_b,
        slot_ctx, state0, stateNew, out);

    // ---- phase 5: new-state K/V rows (paired small GEMM) ----
    kvpair_rows_kernel<<<256, blk, 0, stream>>>(stateNew,
        o_lnkv_g, o_lnkv_b, o_Wk, o_bk, o_Wv, o_bv, kh2, vh2);

    // ---- phase 6: out-branch attention (last token) + head ----
    attn_part_kernel<1><<<256, blk, 0, stream>>>(q2h, kh2, vh2, pmb, plb, paccb);
    comb_gemm_kernel<1><<<256, blk, 0, stream>>>(pmb, plb, paccb,
        o_Wo, o_bo, lo_last, lo1);
    lngemm_kernel<4><<<256, blk, 0, stream>>>(lo1, 0, 1,
        o_lnffn_g, o_lnffn_b, o_fc1_W, o_fc1_b, g2, 1);
    plaingemm_kernel<4><<<256, blk, 0, stream>>>(g2, o_fc2_W, o_fc2_b, lo1, lo2, 0);
    plaingemm_kernel<4><<<256, blk, 0, stream>>>(lo2, op_W, op_b, nullptr, out, 0);
}